// Round 6
// baseline (291.869 us; speedup 1.0000x reference)
//
#include <hip/hip_runtime.h>
#include <hip/hip_bf16.h>

typedef __bf16 bf16_t;
typedef bf16_t bf16x4 __attribute__((ext_vector_type(4)));
typedef bf16_t bf16x8 __attribute__((ext_vector_type(8)));
typedef float floatx4 __attribute__((ext_vector_type(4)));

typedef __attribute__((address_space(1))) const unsigned char* gptr_t;
typedef __attribute__((address_space(3))) unsigned char* lptr_t;

#define BATCH 4
#define SEQ_N 2048
#define SEQ_M 2048
#define DIM 1024
#define INNER 512
#define HEADS 8
#define DHEAD 64
// 0.125 * log2(e): folded into Wq so attention scores arrive in exp2 domain
#define QSCALE 0.18033688011112042f

// ---------------- Fused LayerNorm (x and context in one dispatch) ----------
__global__ __launch_bounds__(256) void ln_fused_kernel(const float* __restrict__ x,
                                                       const float* __restrict__ ctx,
                                                       const float* __restrict__ g1,
                                                       const float* __restrict__ b1,
                                                       const float* __restrict__ g2,
                                                       const float* __restrict__ b2,
                                                       bf16_t* __restrict__ xn,
                                                       bf16_t* __restrict__ cn) {
    const int rid = blockIdx.x;
    const bool is_x = rid < BATCH * SEQ_N;
    const int row = is_x ? rid : rid - BATCH * SEQ_N;
    const float* in = is_x ? x : ctx;
    const float* g  = is_x ? g1 : g2;
    const float* bt = is_x ? b1 : b2;
    bf16_t* out = is_x ? xn : cn;
    const int tid = threadIdx.x;

    float4 xv = ((const float4*)(in + (size_t)row * 1024))[tid];
    float s = xv.x + xv.y + xv.z + xv.w;
    float ss = xv.x * xv.x + xv.y * xv.y + xv.z * xv.z + xv.w * xv.w;
#pragma unroll
    for (int off = 32; off > 0; off >>= 1) {
        s  += __shfl_down(s, off);
        ss += __shfl_down(ss, off);
    }
    __shared__ float red[8];
    const int wave = tid >> 6, lane = tid & 63;
    if (lane == 0) { red[wave] = s; red[4 + wave] = ss; }
    __syncthreads();
    if (tid == 0) {
        float a = red[0] + red[1] + red[2] + red[3];
        float b = red[4] + red[5] + red[6] + red[7];
        red[0] = a * (1.f / 1024.f);
        red[4] = b * (1.f / 1024.f);
    }
    __syncthreads();
    const float mu = red[0];
    const float var = red[4] - mu * mu;
    const float rs = rsqrtf(var + 1e-5f);

    float4 gv = ((const float4*)g)[tid];
    float4 bv = ((const float4*)bt)[tid];
    bf16x4 o;
    o[0] = (bf16_t)((xv.x - mu) * rs * gv.x + bv.x);
    o[1] = (bf16_t)((xv.y - mu) * rs * gv.y + bv.y);
    o[2] = (bf16_t)((xv.z - mu) * rs * gv.z + bv.z);
    o[3] = (bf16_t)((xv.w - mu) * rs * gv.w + bv.w);
    *(bf16x4*)(out + (size_t)row * 1024 + tid * 4) = o;
}

// ---------------- Fused weight convert+transpose (all 3 weights) ----------
__device__ __forceinline__ void wtrans_tile(const float* W, bf16_t* Wt,
                                            int K, int N, int n0, int k0, float scale) {
    __shared__ bf16_t T[64][72];
    const int tid = threadIdx.x;
#pragma unroll
    for (int p = 0; p < 2; p++) {
        int r = (tid >> 3) + p * 32;       // k
        int c = (tid & 7) * 8;             // n
        const float* src = W + (size_t)(k0 + r) * N + n0 + c;
        float4 v0 = *(const float4*)src;
        float4 v1 = *(const float4*)(src + 4);
        T[r][c + 0] = (bf16_t)(v0.x * scale); T[r][c + 1] = (bf16_t)(v0.y * scale);
        T[r][c + 2] = (bf16_t)(v0.z * scale); T[r][c + 3] = (bf16_t)(v0.w * scale);
        T[r][c + 4] = (bf16_t)(v1.x * scale); T[r][c + 5] = (bf16_t)(v1.y * scale);
        T[r][c + 6] = (bf16_t)(v1.z * scale); T[r][c + 7] = (bf16_t)(v1.w * scale);
    }
    __syncthreads();
#pragma unroll
    for (int p = 0; p < 2; p++) {
        int rn = (tid >> 3) + p * 32;      // n
        int ck = (tid & 7) * 8;            // k
        bf16x8 v;
#pragma unroll
        for (int i = 0; i < 8; i++) v[i] = T[ck + i][rn];
        *(bf16x8*)(Wt + (size_t)(n0 + rn) * K + k0 + ck) = v;
    }
}

__global__ __launch_bounds__(256) void wtrans_all_kernel(const float* __restrict__ Wq,
                                                         const float* __restrict__ Wkv,
                                                         const float* __restrict__ Wout,
                                                         bf16_t* __restrict__ Wqt,
                                                         bf16_t* __restrict__ Wkvt,
                                                         bf16_t* __restrict__ Woutt) {
    int id = blockIdx.x;
    if (id < 128) {                 // Wq: K=1024, N=512 (scaled for exp2 domain)
        wtrans_tile(Wq, Wqt, 1024, 512, (id & 7) * 64, (id >> 3) * 64, QSCALE);
    } else if (id < 384) {          // Wkv: K=1024, N=1024
        int t = id - 128;
        wtrans_tile(Wkv, Wkvt, 1024, 1024, (t & 15) * 64, (t >> 4) * 64, 1.0f);
    } else {                        // Wout: K=512, N=1024
        int t = id - 384;
        wtrans_tile(Wout, Woutt, 512, 1024, (t & 15) * 64, (t >> 4) * 64, 1.0f);
    }
}

// ---------------- V transpose ----------------
__global__ __launch_bounds__(256) void vtrans_kernel(const bf16_t* __restrict__ kvb,
                                                     bf16_t* __restrict__ Vt) {
    __shared__ bf16_t T[64][72];
    const int b = blockIdx.z;
    const int m0 = blockIdx.x * 64, d0 = blockIdx.y * 64;
    const int tid = threadIdx.x;
#pragma unroll
    for (int p = 0; p < 2; p++) {
        int r = (tid >> 3) + p * 32;   // m
        int c = (tid & 7) * 8;         // d'
        *(bf16x8*)&T[r][c] =
            *(const bf16x8*)(kvb + (size_t)(b * SEQ_M + m0 + r) * 1024 + INNER + d0 + c);
    }
    __syncthreads();
#pragma unroll
    for (int p = 0; p < 2; p++) {
        int rd = (tid >> 3) + p * 32;  // d'
        int cm = (tid & 7) * 8;        // m
        bf16x8 v;
#pragma unroll
        for (int i = 0; i < 8; i++) v[i] = T[cm + i][rd];
        *(bf16x8*)(Vt + (size_t)(b * INNER + d0 + rd) * SEQ_M + m0 + cm) = v;
    }
}

// ---------------- m97-style GEMM body: C[.,N] tile at (row0,col0) ----------
template <typename OutT>
__device__ __forceinline__ void gemm_body(const bf16_t* __restrict__ A,
                                          const bf16_t* __restrict__ Bt,
                                          OutT* __restrict__ C,
                                          const float* __restrict__ bias,
                                          int N, int K, int row0, int col0) {
    __shared__ bf16_t As[128 * 64];
    __shared__ bf16_t Bs[128 * 64];
    const int tid = threadIdx.x;
    const int wave = tid >> 6, lane = tid & 63;
    const int wr = (wave >> 1) * 64, wc = (wave & 1) * 64;
    const int quad = lane >> 4, l16 = lane & 15;

    floatx4 acc[4][4] = {};

    for (int k0 = 0; k0 < K; k0 += 64) {
#pragma unroll
        for (int p = 0; p < 4; p++) {
            int cA = p * 256 + wave * 64 + lane;
            int rA = cA >> 3, kc = (cA & 7) * 8;
            __builtin_amdgcn_global_load_lds(
                (gptr_t)(A + (size_t)(row0 + rA) * K + k0 + kc),
                (lptr_t)(As + (size_t)(p * 256 + wave * 64) * 8), 16, 0, 0);
            __builtin_amdgcn_global_load_lds(
                (gptr_t)(Bt + (size_t)(col0 + rA) * K + k0 + kc),
                (lptr_t)(Bs + (size_t)(p * 256 + wave * 64) * 8), 16, 0, 0);
        }
        __syncthreads();
#pragma unroll
        for (int kt = 0; kt < 2; kt++) {
            bf16x8 aF[4], bF[4];
#pragma unroll
            for (int i = 0; i < 4; i++)
                aF[i] = *(bf16x8*)&As[(wr + i * 16 + l16) * 64 + kt * 32 + quad * 8];
#pragma unroll
            for (int j = 0; j < 4; j++)
                bF[j] = *(bf16x8*)&Bs[(wc + j * 16 + l16) * 64 + kt * 32 + quad * 8];
#pragma unroll
            for (int i = 0; i < 4; i++)
#pragma unroll
                for (int j = 0; j < 4; j++)
                    acc[i][j] = __builtin_amdgcn_mfma_f32_16x16x32_bf16(
                        aF[i], bF[j], acc[i][j], 0, 0, 0);
        }
        __syncthreads();
    }

#pragma unroll
    for (int i = 0; i < 4; i++)
#pragma unroll
        for (int j = 0; j < 4; j++) {
            int col = col0 + wc + j * 16 + l16;
            float bv = bias ? bias[col] : 0.f;
#pragma unroll
            for (int r = 0; r < 4; r++) {
                int row = row0 + wr + i * 16 + quad * 4 + r;
                C[(size_t)row * N + col] = (OutT)(acc[i][j][r] + bv);
            }
        }
}

// Fused q-proj + kv-proj: blockIdx.x 0..3 -> q tiles, 4..11 -> kv tiles
__global__ __launch_bounds__(256) void gemm_qkv_kernel(const bf16_t* __restrict__ xn,
                                                       const bf16_t* __restrict__ cn,
                                                       const bf16_t* __restrict__ Wqt,
                                                       const bf16_t* __restrict__ Wkvt,
                                                       bf16_t* __restrict__ qb,
                                                       bf16_t* __restrict__ kvb) {
    const int bx = blockIdx.x;
    const int row0 = blockIdx.y * 128;
    if (bx < 4)
        gemm_body<bf16_t>(xn, Wqt, qb, nullptr, INNER, DIM, row0, bx * 128);
    else
        gemm_body<bf16_t>(cn, Wkvt, kvb, nullptr, 2 * INNER, DIM, row0, (bx - 4) * 128);
}

__global__ __launch_bounds__(256) void gemm_out_kernel(const bf16_t* __restrict__ ao,
                                                       const bf16_t* __restrict__ Woutt,
                                                       float* __restrict__ out,
                                                       const float* __restrict__ bias) {
    gemm_body<float>(ao, Woutt, out, bias, DIM, INNER, blockIdx.y * 128, blockIdx.x * 128);
}

// ---------------- Flash attention, fixed-base exp2, S^T + packed P stores --
// 128-row q-tile per block; wave owns 2 q-subtiles (rows w*16.. and 64+w*16..).
// S^T = mfma(A=K-frag, B=Q-frag) -> lane holds S^T[j=jt*16+quad*4+r][q=l16];
// r is memory-consecutive under P[q][m] layout -> 4x ds_write_b64 per subtile.
// PV reads P[q][m] rows as aligned b128 A-frags. l via MFMA ones-column.
#define PSTR 72   // P row stride (16B-aligned rows; store/read banks even-spread)
__global__ __launch_bounds__(256) void attn_kernel(const bf16_t* __restrict__ q,
                                                   const bf16_t* __restrict__ kv,
                                                   const bf16_t* __restrict__ Vtg,
                                                   bf16_t* __restrict__ o) {
    __shared__ bf16_t Qbuf[128 * 72]; // Q staging [qrow][d]; reused as P buffers
    __shared__ bf16_t Ks[64 * 72];    // [krow][d]
    __shared__ bf16_t Vs[80 * 72];    // [d][krow]; rows 64..79: ones-column tile

    const int b = blockIdx.z, h = blockIdx.y;
    const int n0 = blockIdx.x * 128;
    const int tid = threadIdx.x;
    const int wave = tid >> 6, lane = tid & 63;
    const int quad = lane >> 4, l16 = lane & 15;

    // stage Q tile [128][64]
#pragma unroll
    for (int p = 0; p < 4; p++) {
        int r = (tid >> 3) + p * 32;
        int c = (tid & 7) * 8;
        *(bf16x8*)&Qbuf[r * 72 + c] =
            *(const bf16x8*)(q + (size_t)(b * SEQ_N + n0 + r) * INNER + h * DHEAD + c);
    }
    // ones tile: Vs rows 64..79 (row 64 = 1, rest = 0), written once
#pragma unroll
    for (int i = 0; i < 4; i++) {
        int idx = i * 256 + tid;            // 0..1023
        int r = 64 + (idx >> 6), c = idx & 63;
        Vs[r * 72 + c] = (r == 64) ? (bf16_t)1.0f : (bf16_t)0.0f;
    }
    __syncthreads();

    // Q fragments for both subtiles (read before Qbuf is reused for P)
    bf16x8 aQ[2][2];
#pragma unroll
    for (int sub = 0; sub < 2; sub++)
#pragma unroll
        for (int kt = 0; kt < 2; kt++)
            aQ[sub][kt] = *(bf16x8*)&Qbuf[(sub * 64 + wave * 16 + l16) * 72 + kt * 32 + quad * 8];

    // per-wave P buffers: 2 subtiles x [16 q][PSTR m]; aliases Qbuf (4*2*16*72 = 9216)
    bf16_t* Pw0 = Qbuf + wave * (2 * 16 * PSTR);
    bf16_t* Pw1 = Pw0 + 16 * PSTR;

    floatx4 oacc[2][5] = {};  // [sub][0..3]=O d-tiles (unnormalized), [4]=l (col 0)

    for (int m0 = 0; m0 < SEQ_M; m0 += 64) {
        __syncthreads();
#pragma unroll
        for (int p = 0; p < 2; p++) {
            int r = (tid >> 3) + p * 32;
            int c = (tid & 7) * 8;
            *(bf16x8*)&Ks[r * 72 + c] =
                *(const bf16x8*)(kv + (size_t)(b * SEQ_M + m0 + r) * 1024 + h * DHEAD + c);
            *(bf16x8*)&Vs[r * 72 + c] =
                *(const bf16x8*)(Vtg + (size_t)((b * HEADS + h) * DHEAD + r) * SEQ_M + m0 + c);
        }
        __syncthreads();

        // S^T = K @ Q^T (exp2 domain): s[sub][jt] rows j, cols q
        floatx4 s[2][4] = {};
#pragma unroll
        for (int kt = 0; kt < 2; kt++)
#pragma unroll
            for (int jt = 0; jt < 4; jt++) {
                bf16x8 aK = *(bf16x8*)&Ks[(jt * 16 + l16) * 72 + kt * 32 + quad * 8];
                s[0][jt] = __builtin_amdgcn_mfma_f32_16x16x32_bf16(aK, aQ[0][kt], s[0][jt], 0, 0, 0);
                s[1][jt] = __builtin_amdgcn_mfma_f32_16x16x32_bf16(aK, aQ[1][kt], s[1][jt], 0, 0, 0);
            }

        // P = exp2(S^T): packed b64 stores (r=0..3 consecutive at [q=l16][m=jt*16+quad*4])
#pragma unroll
        for (int jt = 0; jt < 4; jt++) {
            bf16x4 p0, p1;
#pragma unroll
            for (int r = 0; r < 4; r++) {
                p0[r] = (bf16_t)exp2f(s[0][jt][r]);
                p1[r] = (bf16_t)exp2f(s[1][jt][r]);
            }
            *(bf16x4*)&Pw0[l16 * PSTR + jt * 16 + quad * 4] = p0;
            *(bf16x4*)&Pw1[l16 * PSTR + jt * 16 + quad * 4] = p1;
        }

        // O += P @ V  (dt=4 accumulates l via ones column); bV shared across subs
#pragma unroll
        for (int kt = 0; kt < 2; kt++) {
            bf16x8 aP0 = *(bf16x8*)&Pw0[l16 * PSTR + kt * 32 + quad * 8];
            bf16x8 aP1 = *(bf16x8*)&Pw1[l16 * PSTR + kt * 32 + quad * 8];
#pragma unroll
            for (int dt = 0; dt < 5; dt++) {
                bf16x8 bV = *(bf16x8*)&Vs[(dt * 16 + l16) * 72 + kt * 32 + quad * 8];
                oacc[0][dt] = __builtin_amdgcn_mfma_f32_16x16x32_bf16(aP0, bV, oacc[0][dt], 0, 0, 0);
                oacc[1][dt] = __builtin_amdgcn_mfma_f32_16x16x32_bf16(aP1, bV, oacc[1][dt], 0, 0, 0);
            }
        }
    }

    // epilogue: l lives in oacc[sub][4] col 0 (lanes l16==0); broadcast within quad
#pragma unroll
    for (int sub = 0; sub < 2; sub++) {
        float inv[4];
#pragma unroll
        for (int r = 0; r < 4; r++) {
            float l = __shfl(oacc[sub][4][r], (int)(lane & 48));
            inv[r] = 1.0f / l;
        }
#pragma unroll
        for (int dt = 0; dt < 4; dt++)
#pragma unroll
            for (int r = 0; r < 4; r++) {
                int row = n0 + sub * 64 + wave * 16 + quad * 4 + r;
                int col = h * DHEAD + dt * 16 + l16;
                o[(size_t)(b * SEQ_N + row) * INNER + col] =
                    (bf16_t)(oacc[sub][dt][r] * inv[r]);
            }
    }
}

extern "C" void kernel_launch(void* const* d_in, const int* in_sizes, int n_in,
                              void* d_out, int out_size, void* d_ws, size_t ws_size,
                              hipStream_t stream) {
    const float* x    = (const float*)d_in[0];
    const float* ctx  = (const float*)d_in[1];
    const float* g1   = (const float*)d_in[2];
    const float* b1   = (const float*)d_in[3];
    const float* g2   = (const float*)d_in[4];
    const float* b2   = (const float*)d_in[5];
    const float* Wq   = (const float*)d_in[6];
    const float* Wkv  = (const float*)d_in[7];
    const float* Wout = (const float*)d_in[8];
    const float* bout = (const float*)d_in[9];
    float* out = (float*)d_out;

    const int rows = BATCH * SEQ_N;  // 8192
    bf16_t* xn    = (bf16_t*)d_ws;                       // 8M elem
    bf16_t* cn    = xn + (size_t)rows * DIM;             // 8M (reused as Vt)
    bf16_t* qb    = cn + (size_t)rows * DIM;             // 4M
    bf16_t* kvb   = qb + (size_t)rows * INNER;           // 8M
    bf16_t* ao    = kvb + (size_t)rows * (2 * INNER);    // 4M
    bf16_t* Wqt   = ao + (size_t)rows * INNER;           // 0.5M
    bf16_t* Wkvt  = Wqt + (size_t)INNER * DIM;           // 1M
    bf16_t* Woutt = Wkvt + (size_t)(2 * INNER) * DIM;    // 0.5M
    bf16_t* Vtg   = cn;  // alias: cn dead after qkv GEMM

    wtrans_all_kernel<<<512, 256, 0, stream>>>(Wq, Wkv, Wout, Wqt, Wkvt, Woutt);
    ln_fused_kernel<<<2 * rows, 256, 0, stream>>>(x, ctx, g1, b1, g2, b2, xn, cn);
    gemm_qkv_kernel<<<dim3(12, rows / 128), 256, 0, stream>>>(xn, cn, Wqt, Wkvt, qb, kvb);
    vtrans_kernel<<<dim3(SEQ_M / 64, INNER / 64, BATCH), 256, 0, stream>>>(kvb, Vtg);
    attn_kernel<<<dim3(SEQ_N / 128, HEADS, BATCH), 256, 0, stream>>>(qb, kvb, Vtg, ao);
    gemm_out_kernel<<<dim3(DIM / 128, rows / 128), 256, 0, stream>>>(ao, Woutt, out, bout);
}

// Round 7
// 263.496 us; speedup vs baseline: 1.1077x; 1.1077x over previous
//
#include <hip/hip_runtime.h>
#include <hip/hip_bf16.h>

typedef __bf16 bf16_t;
typedef bf16_t bf16x4 __attribute__((ext_vector_type(4)));
typedef bf16_t bf16x8 __attribute__((ext_vector_type(8)));
typedef float floatx4 __attribute__((ext_vector_type(4)));

typedef __attribute__((address_space(1))) const unsigned char* gptr_t;
typedef __attribute__((address_space(3))) unsigned char* lptr_t;

#define BATCH 4
#define SEQ_N 2048
#define SEQ_M 2048
#define DIM 1024
#define INNER 512
#define HEADS 8
#define DHEAD 64
// 0.125 * log2(e): folded into Wq so attention scores arrive in exp2 domain
#define QSCALE 0.18033688011112042f

// ---------------- Prep: weight convert+transpose AND LayerNorm, one dispatch
__device__ __forceinline__ void wtrans_tile(const float* W, bf16_t* Wt,
                                            int K, int N, int n0, int k0, float scale) {
    __shared__ bf16_t T[64][72];
    const int tid = threadIdx.x;
#pragma unroll
    for (int p = 0; p < 2; p++) {
        int r = (tid >> 3) + p * 32;       // k
        int c = (tid & 7) * 8;             // n
        const float* src = W + (size_t)(k0 + r) * N + n0 + c;
        float4 v0 = *(const float4*)src;
        float4 v1 = *(const float4*)(src + 4);
        T[r][c + 0] = (bf16_t)(v0.x * scale); T[r][c + 1] = (bf16_t)(v0.y * scale);
        T[r][c + 2] = (bf16_t)(v0.z * scale); T[r][c + 3] = (bf16_t)(v0.w * scale);
        T[r][c + 4] = (bf16_t)(v1.x * scale); T[r][c + 5] = (bf16_t)(v1.y * scale);
        T[r][c + 6] = (bf16_t)(v1.z * scale); T[r][c + 7] = (bf16_t)(v1.w * scale);
    }
    __syncthreads();
#pragma unroll
    for (int p = 0; p < 2; p++) {
        int rn = (tid >> 3) + p * 32;      // n
        int ck = (tid & 7) * 8;            // k
        bf16x8 v;
#pragma unroll
        for (int i = 0; i < 8; i++) v[i] = T[ck + i][rn];
        *(bf16x8*)(Wt + (size_t)(n0 + rn) * K + k0 + ck) = v;
    }
}

__device__ __forceinline__ void ln_row(const float* in, const float* g,
                                       const float* bt, bf16_t* out, int row) {
    const int tid = threadIdx.x;
    float4 xv = ((const float4*)(in + (size_t)row * 1024))[tid];
    float s = xv.x + xv.y + xv.z + xv.w;
    float ss = xv.x * xv.x + xv.y * xv.y + xv.z * xv.z + xv.w * xv.w;
#pragma unroll
    for (int off = 32; off > 0; off >>= 1) {
        s  += __shfl_down(s, off);
        ss += __shfl_down(ss, off);
    }
    __shared__ float red[8];
    const int wave = tid >> 6, lane = tid & 63;
    if (lane == 0) { red[wave] = s; red[4 + wave] = ss; }
    __syncthreads();
    if (tid == 0) {
        float a = red[0] + red[1] + red[2] + red[3];
        float b = red[4] + red[5] + red[6] + red[7];
        red[0] = a * (1.f / 1024.f);
        red[4] = b * (1.f / 1024.f);
    }
    __syncthreads();
    const float mu = red[0];
    const float var = red[4] - mu * mu;
    const float rs = rsqrtf(var + 1e-5f);

    float4 gv = ((const float4*)g)[tid];
    float4 bv = ((const float4*)bt)[tid];
    bf16x4 o;
    o[0] = (bf16_t)((xv.x - mu) * rs * gv.x + bv.x);
    o[1] = (bf16_t)((xv.y - mu) * rs * gv.y + bv.y);
    o[2] = (bf16_t)((xv.z - mu) * rs * gv.z + bv.z);
    o[3] = (bf16_t)((xv.w - mu) * rs * gv.w + bv.w);
    *(bf16x4*)(out + (size_t)row * 1024 + tid * 4) = o;
}

__global__ __launch_bounds__(256) void prep_kernel(const float* __restrict__ x,
                                                   const float* __restrict__ ctx,
                                                   const float* __restrict__ g1,
                                                   const float* __restrict__ b1,
                                                   const float* __restrict__ g2,
                                                   const float* __restrict__ b2,
                                                   const float* __restrict__ Wq,
                                                   const float* __restrict__ Wkv,
                                                   const float* __restrict__ Wout,
                                                   bf16_t* __restrict__ xn,
                                                   bf16_t* __restrict__ cn,
                                                   bf16_t* __restrict__ Wqt,
                                                   bf16_t* __restrict__ Wkvt,
                                                   bf16_t* __restrict__ Woutt) {
    int id = blockIdx.x;
    if (id < 128) {
        wtrans_tile(Wq, Wqt, 1024, 512, (id & 7) * 64, (id >> 3) * 64, QSCALE);
    } else if (id < 384) {
        int t = id - 128;
        wtrans_tile(Wkv, Wkvt, 1024, 1024, (t & 15) * 64, (t >> 4) * 64, 1.0f);
    } else if (id < 512) {
        int t = id - 384;
        wtrans_tile(Wout, Woutt, 512, 1024, (t & 15) * 64, (t >> 4) * 64, 1.0f);
    } else {
        int rid = id - 512;
        if (rid < BATCH * SEQ_N) ln_row(x, g1, b1, xn, rid);
        else                     ln_row(ctx, g2, b2, cn, rid - BATCH * SEQ_N);
    }
}

// ---------------- m97-style GEMM body ----------------
// MODE 0: C[row*ldC + col] (+bias). MODE 1: transposed-output (V^T) — compute
// D^T via operand swap, scatter to C[( (grow>>11)*512 + (col-512) )*2048 + (grow&2047)].
template <int MODE, typename OutT>
__device__ __forceinline__ void gemm_body(const bf16_t* __restrict__ A,
                                          const bf16_t* __restrict__ Bt,
                                          OutT* __restrict__ C,
                                          const float* __restrict__ bias,
                                          int ldC, int K, int row0, int col0) {
    __shared__ bf16_t As[128 * 64];
    __shared__ bf16_t Bs[128 * 64];
    const int tid = threadIdx.x;
    const int wave = tid >> 6, lane = tid & 63;
    const int wr = (wave >> 1) * 64, wc = (wave & 1) * 64;
    const int quad = lane >> 4, l16 = lane & 15;

    floatx4 acc[4][4] = {};

    for (int k0 = 0; k0 < K; k0 += 64) {
#pragma unroll
        for (int p = 0; p < 4; p++) {
            int cA = p * 256 + wave * 64 + lane;
            int rA = cA >> 3, kc = (cA & 7) * 8;
            __builtin_amdgcn_global_load_lds(
                (gptr_t)(A + (size_t)(row0 + rA) * K + k0 + kc),
                (lptr_t)(As + (size_t)(p * 256 + wave * 64) * 8), 16, 0, 0);
            __builtin_amdgcn_global_load_lds(
                (gptr_t)(Bt + (size_t)(col0 + rA) * K + k0 + kc),
                (lptr_t)(Bs + (size_t)(p * 256 + wave * 64) * 8), 16, 0, 0);
        }
        __syncthreads();
#pragma unroll
        for (int kt = 0; kt < 2; kt++) {
            bf16x8 aF[4], bF[4];
#pragma unroll
            for (int i = 0; i < 4; i++)
                aF[i] = *(bf16x8*)&As[(wr + i * 16 + l16) * 64 + kt * 32 + quad * 8];
#pragma unroll
            for (int j = 0; j < 4; j++)
                bF[j] = *(bf16x8*)&Bs[(wc + j * 16 + l16) * 64 + kt * 32 + quad * 8];
#pragma unroll
            for (int i = 0; i < 4; i++)
#pragma unroll
                for (int j = 0; j < 4; j++) {
                    if (MODE == 0)
                        acc[i][j] = __builtin_amdgcn_mfma_f32_16x16x32_bf16(
                            aF[i], bF[j], acc[i][j], 0, 0, 0);
                    else  // transposed output: D^T = (B^T A^T)
                        acc[i][j] = __builtin_amdgcn_mfma_f32_16x16x32_bf16(
                            bF[j], aF[i], acc[i][j], 0, 0, 0);
                }
        }
        __syncthreads();
    }

    if (MODE == 0) {
#pragma unroll
        for (int i = 0; i < 4; i++)
#pragma unroll
            for (int j = 0; j < 4; j++) {
                int col = col0 + wc + j * 16 + l16;
                float bv = bias ? bias[col] : 0.f;
#pragma unroll
                for (int r = 0; r < 4; r++) {
                    int row = row0 + wr + i * 16 + quad * 4 + r;
                    C[(size_t)row * ldC + col] = (OutT)(acc[i][j][r] + bv);
                }
            }
    } else {
        // lane holds D^T[d' = wc+j*16+quad*4+r][grow = row0+wr+i*16+l16]
#pragma unroll
        for (int i = 0; i < 4; i++) {
            int grow = row0 + wr + i * 16 + l16;
            int bat = grow >> 11, m = grow & 2047;
#pragma unroll
            for (int j = 0; j < 4; j++)
#pragma unroll
                for (int r = 0; r < 4; r++) {
                    int d = col0 + wc + j * 16 + quad * 4 + r - 512;
                    C[((size_t)bat * 512 + d) * 2048 + m] = (OutT)acc[i][j][r];
                }
        }
    }
}

// Fused q/k/v projections: bx 0..3 q -> qb; 4..7 K -> kvb (ld 512); 8..11 V -> Vtg (transposed)
__global__ __launch_bounds__(256) void gemm_qkv_kernel(const bf16_t* __restrict__ xn,
                                                       const bf16_t* __restrict__ cn,
                                                       const bf16_t* __restrict__ Wqt,
                                                       const bf16_t* __restrict__ Wkvt,
                                                       bf16_t* __restrict__ qb,
                                                       bf16_t* __restrict__ kvb,
                                                       bf16_t* __restrict__ Vtg) {
    const int bx = blockIdx.x;
    const int row0 = blockIdx.y * 128;
    if (bx < 4)
        gemm_body<0, bf16_t>(xn, Wqt, qb, nullptr, 512, DIM, row0, bx * 128);
    else if (bx < 8)
        gemm_body<0, bf16_t>(cn, Wkvt, kvb, nullptr, 512, DIM, row0, (bx - 4) * 128);
    else
        gemm_body<1, bf16_t>(cn, Wkvt, Vtg, nullptr, 0, DIM, row0, (bx - 4) * 128);
}

__global__ __launch_bounds__(256) void gemm_out_kernel(const bf16_t* __restrict__ ao,
                                                       const bf16_t* __restrict__ Woutt,
                                                       float* __restrict__ out,
                                                       const float* __restrict__ bias) {
    gemm_body<0, float>(ao, Woutt, out, bias, DIM, INNER, blockIdx.y * 128, blockIdx.x * 128);
}

// ---------------- Flash attention: fixed-base exp2, S^T packed P, K/V reg-prefetch
// q: [b,n,512]; kvb: [b,m,512] K-only; Vtg: [(b*8+h)*64+d][m]. o: [b,n,512].
// 64 q rows per block (4 blocks/CU), wave w owns rows w*16..w*16+15.
#define PSTR 72
__global__ __launch_bounds__(256) void attn_kernel(const bf16_t* __restrict__ q,
                                                   const bf16_t* __restrict__ kv,
                                                   const bf16_t* __restrict__ Vtg,
                                                   bf16_t* __restrict__ o) {
    __shared__ bf16_t Qs[64 * 72];    // Q staging; reused as per-wave P buffers
    __shared__ bf16_t Ks[64 * 72];    // [krow][d]
    __shared__ bf16_t Vs[80 * 72];    // [d][krow]; rows 64..79: ones-column tile

    const int b = blockIdx.z, h = blockIdx.y;
    const int n0 = blockIdx.x * 64;
    const int tid = threadIdx.x;
    const int wave = tid >> 6, lane = tid & 63;
    const int quad = lane >> 4, l16 = lane & 15;

    const int sr = (tid >> 3);          // staging row base (0..31)
    const int sc = (tid & 7) * 8;       // staging col

    // stage Q tile [64][64]
#pragma unroll
    for (int p = 0; p < 2; p++) {
        int r = sr + p * 32;
        *(bf16x8*)&Qs[r * 72 + sc] =
            *(const bf16x8*)(q + (size_t)(b * SEQ_N + n0 + r) * INNER + h * DHEAD + sc);
    }
    // ones tile: Vs rows 64..79 (row 64 = 1, rest = 0)
#pragma unroll
    for (int i = 0; i < 4; i++) {
        int idx = i * 256 + tid;
        int r = 64 + (idx >> 6), c = idx & 63;
        Vs[r * 72 + c] = (r == 64) ? (bf16_t)1.0f : (bf16_t)0.0f;
    }

    // prefetch K/V tile 0 into registers
    bf16x8 kreg[2], vreg[2];
#pragma unroll
    for (int p = 0; p < 2; p++) {
        int r = sr + p * 32;
        kreg[p] = *(const bf16x8*)(kv + (size_t)(b * SEQ_M + r) * 512 + h * DHEAD + sc);
        vreg[p] = *(const bf16x8*)(Vtg + (size_t)((b * HEADS + h) * DHEAD + r) * SEQ_M + sc);
    }
    __syncthreads();

    bf16x8 aQ[2];
#pragma unroll
    for (int kt = 0; kt < 2; kt++)
        aQ[kt] = *(bf16x8*)&Qs[(wave * 16 + l16) * 72 + kt * 32 + quad * 8];

    bf16_t* Pw = Qs + wave * (16 * PSTR);   // per-wave P buffer aliasing Qs

    floatx4 oacc[5] = {};   // [0..3]=O d-tiles (unnormalized), [4]=l (col 0)

    for (int it = 0; it < SEQ_M / 64; ++it) {
        __syncthreads();    // prior-iter LDS reads done (and iter0: aQ reads done)
#pragma unroll
        for (int p = 0; p < 2; p++) {
            int r = sr + p * 32;
            *(bf16x8*)&Ks[r * 72 + sc] = kreg[p];
            *(bf16x8*)&Vs[r * 72 + sc] = vreg[p];
        }
        __syncthreads();

        if (it + 1 < SEQ_M / 64) {
            int m0 = (it + 1) * 64;
#pragma unroll
            for (int p = 0; p < 2; p++) {
                int r = sr + p * 32;
                kreg[p] = *(const bf16x8*)(kv + (size_t)(b * SEQ_M + m0 + r) * 512 + h * DHEAD + sc);
                vreg[p] = *(const bf16x8*)(Vtg + (size_t)((b * HEADS + h) * DHEAD + r) * SEQ_M + m0 + sc);
            }
        }

        // S^T = K @ Q^T (exp2 domain): lane holds S^T[j=jt*16+quad*4+r][q=l16]
        floatx4 s[4] = {};
#pragma unroll
        for (int kt = 0; kt < 2; kt++)
#pragma unroll
            for (int jt = 0; jt < 4; jt++) {
                bf16x8 aK = *(bf16x8*)&Ks[(jt * 16 + l16) * 72 + kt * 32 + quad * 8];
                s[jt] = __builtin_amdgcn_mfma_f32_16x16x32_bf16(aK, aQ[kt], s[jt], 0, 0, 0);
            }

        // P = exp2(S^T): packed b64 stores at P[q=l16][m=jt*16+quad*4]
#pragma unroll
        for (int jt = 0; jt < 4; jt++) {
            bf16x4 pk;
#pragma unroll
            for (int r = 0; r < 4; r++) pk[r] = (bf16_t)exp2f(s[jt][r]);
            *(bf16x4*)&Pw[l16 * PSTR + jt * 16 + quad * 4] = pk;
        }

        // O += P @ V (dt=4 accumulates l via ones column)
#pragma unroll
        for (int kt = 0; kt < 2; kt++) {
            bf16x8 aP = *(bf16x8*)&Pw[l16 * PSTR + kt * 32 + quad * 8];
#pragma unroll
            for (int dt = 0; dt < 5; dt++) {
                bf16x8 bV = *(bf16x8*)&Vs[(dt * 16 + l16) * 72 + kt * 32 + quad * 8];
                oacc[dt] = __builtin_amdgcn_mfma_f32_16x16x32_bf16(aP, bV, oacc[dt], 0, 0, 0);
            }
        }
    }

    // epilogue: l in oacc[4] col 0 (lanes l16==0); broadcast within quad-row group
    float inv[4];
#pragma unroll
    for (int r = 0; r < 4; r++) {
        float l = __shfl(oacc[4][r], (int)(lane & 48));
        inv[r] = 1.0f / l;
    }
#pragma unroll
    for (int dt = 0; dt < 4; dt++)
#pragma unroll
        for (int r = 0; r < 4; r++) {
            int row = n0 + wave * 16 + quad * 4 + r;
            int col = h * DHEAD + dt * 16 + l16;
            o[(size_t)(b * SEQ_N + row) * INNER + col] =
                (bf16_t)(oacc[dt][r] * inv[r]);
        }
}

extern "C" void kernel_launch(void* const* d_in, const int* in_sizes, int n_in,
                              void* d_out, int out_size, void* d_ws, size_t ws_size,
                              hipStream_t stream) {
    const float* x    = (const float*)d_in[0];
    const float* ctx  = (const float*)d_in[1];
    const float* g1   = (const float*)d_in[2];
    const float* b1   = (const float*)d_in[3];
    const float* g2   = (const float*)d_in[4];
    const float* b2   = (const float*)d_in[5];
    const float* Wq   = (const float*)d_in[6];
    const float* Wkv  = (const float*)d_in[7];
    const float* Wout = (const float*)d_in[8];
    const float* bout = (const float*)d_in[9];
    float* out = (float*)d_out;

    const int rows = BATCH * SEQ_N;  // 8192
    bf16_t* xn    = (bf16_t*)d_ws;                       // 8M elem; first 4M reused as attn out
    bf16_t* cn    = xn + (size_t)rows * DIM;             // 8M
    bf16_t* qb    = cn + (size_t)rows * DIM;             // 4M
    bf16_t* kvb   = qb + (size_t)rows * INNER;           // 4M (K only, stride 512)
    bf16_t* Vtg   = kvb + (size_t)rows * INNER;          // 4M (V transposed)
    bf16_t* Wqt   = Vtg + (size_t)rows * INNER;          // 0.5M
    bf16_t* Wkvt  = Wqt + (size_t)INNER * DIM;           // 1M
    bf16_t* Woutt = Wkvt + (size_t)(2 * INNER) * DIM;    // 0.5M
    bf16_t* o_attn = xn;  // alias: xn dead after qkv GEMM

    prep_kernel<<<512 + 2 * rows, 256, 0, stream>>>(
        x, ctx, g1, b1, g2, b2, Wq, Wkv, Wout, xn, cn, Wqt, Wkvt, Woutt);
    gemm_qkv_kernel<<<dim3(12, rows / 128), 256, 0, stream>>>(
        xn, cn, Wqt, Wkvt, qb, kvb, Vtg);
    attn_kernel<<<dim3(SEQ_N / 64, HEADS, BATCH), 256, 0, stream>>>(qb, kvb, Vtg, o_attn);
    gemm_out_kernel<<<dim3(DIM / 128, rows / 128), 256, 0, stream>>>(o_attn, Woutt, out, bout);
}

// Round 8
// 259.625 us; speedup vs baseline: 1.1242x; 1.0149x over previous
//
#include <hip/hip_runtime.h>
#include <hip/hip_bf16.h>

typedef __bf16 bf16_t;
typedef bf16_t bf16x4 __attribute__((ext_vector_type(4)));
typedef bf16_t bf16x8 __attribute__((ext_vector_type(8)));
typedef float floatx4 __attribute__((ext_vector_type(4)));

typedef __attribute__((address_space(1))) const unsigned char* gptr_t;
typedef __attribute__((address_space(3))) unsigned char* lptr_t;

#define BATCH 4
#define SEQ_N 2048
#define SEQ_M 2048
#define DIM 1024
#define INNER 512
#define HEADS 8
#define DHEAD 64
// 0.125 * log2(e): folded into Wq so attention scores arrive in exp2 domain
#define QSCALE 0.18033688011112042f

// ---------------- Prep: weight convert+transpose AND LayerNorm, one dispatch
__device__ __forceinline__ void wtrans_tile(const float* W, bf16_t* Wt,
                                            int K, int N, int n0, int k0, float scale) {
    __shared__ bf16_t T[64][72];
    const int tid = threadIdx.x;
#pragma unroll
    for (int p = 0; p < 2; p++) {
        int r = (tid >> 3) + p * 32;       // k
        int c = (tid & 7) * 8;             // n
        const float* src = W + (size_t)(k0 + r) * N + n0 + c;
        float4 v0 = *(const float4*)src;
        float4 v1 = *(const float4*)(src + 4);
        T[r][c + 0] = (bf16_t)(v0.x * scale); T[r][c + 1] = (bf16_t)(v0.y * scale);
        T[r][c + 2] = (bf16_t)(v0.z * scale); T[r][c + 3] = (bf16_t)(v0.w * scale);
        T[r][c + 4] = (bf16_t)(v1.x * scale); T[r][c + 5] = (bf16_t)(v1.y * scale);
        T[r][c + 6] = (bf16_t)(v1.z * scale); T[r][c + 7] = (bf16_t)(v1.w * scale);
    }
    __syncthreads();
#pragma unroll
    for (int p = 0; p < 2; p++) {
        int rn = (tid >> 3) + p * 32;      // n
        int ck = (tid & 7) * 8;            // k
        bf16x8 v;
#pragma unroll
        for (int i = 0; i < 8; i++) v[i] = T[ck + i][rn];
        *(bf16x8*)(Wt + (size_t)(n0 + rn) * K + k0 + ck) = v;
    }
}

// One LN row per wave: shuffle-only reduction, no barriers, no LDS.
__device__ __forceinline__ void ln_row_wave(const float* in, const float* g,
                                            const float* bt, bf16_t* out, int row) {
    const int lane = threadIdx.x & 63;
    const float4* src = (const float4*)(in + (size_t)row * 1024);
    float4 xv[4];
    float s = 0.f, ss = 0.f;
#pragma unroll
    for (int k = 0; k < 4; k++) {
        xv[k] = src[lane + k * 64];
        s  += xv[k].x + xv[k].y + xv[k].z + xv[k].w;
        ss += xv[k].x * xv[k].x + xv[k].y * xv[k].y + xv[k].z * xv[k].z + xv[k].w * xv[k].w;
    }
#pragma unroll
    for (int off = 32; off > 0; off >>= 1) {
        s  += __shfl_down(s, off);
        ss += __shfl_down(ss, off);
    }
    s  = __shfl(s, 0);
    ss = __shfl(ss, 0);
    const float mu = s * (1.f / 1024.f);
    const float var = ss * (1.f / 1024.f) - mu * mu;
    const float rs = rsqrtf(var + 1e-5f);
    const float4* gp = (const float4*)g;
    const float4* bp = (const float4*)bt;
#pragma unroll
    for (int k = 0; k < 4; k++) {
        float4 gv = gp[lane + k * 64], bv = bp[lane + k * 64];
        bf16x4 o;
        o[0] = (bf16_t)((xv[k].x - mu) * rs * gv.x + bv.x);
        o[1] = (bf16_t)((xv[k].y - mu) * rs * gv.y + bv.y);
        o[2] = (bf16_t)((xv[k].z - mu) * rs * gv.z + bv.z);
        o[3] = (bf16_t)((xv[k].w - mu) * rs * gv.w + bv.w);
        *(bf16x4*)(out + (size_t)row * 1024 + (lane + k * 64) * 4) = o;
    }
}

__global__ __launch_bounds__(256) void prep_kernel(const float* __restrict__ x,
                                                   const float* __restrict__ ctx,
                                                   const float* __restrict__ g1,
                                                   const float* __restrict__ b1,
                                                   const float* __restrict__ g2,
                                                   const float* __restrict__ b2,
                                                   const float* __restrict__ Wq,
                                                   const float* __restrict__ Wkv,
                                                   const float* __restrict__ Wout,
                                                   bf16_t* __restrict__ xn,
                                                   bf16_t* __restrict__ cn,
                                                   bf16_t* __restrict__ Wqt,
                                                   bf16_t* __restrict__ Wkvt,
                                                   bf16_t* __restrict__ Woutt) {
    int id = blockIdx.x;
    if (id < 128) {
        wtrans_tile(Wq, Wqt, 1024, 512, (id & 7) * 64, (id >> 3) * 64, QSCALE);
    } else if (id < 384) {
        int t = id - 128;
        wtrans_tile(Wkv, Wkvt, 1024, 1024, (t & 15) * 64, (t >> 4) * 64, 1.0f);
    } else if (id < 512) {
        int t = id - 384;
        wtrans_tile(Wout, Woutt, 512, 1024, (t & 15) * 64, (t >> 4) * 64, 1.0f);
    } else {
        int row = (id - 512) * 4 + (threadIdx.x >> 6);   // one row per wave
        if (row < BATCH * SEQ_N) ln_row_wave(x, g1, b1, xn, row);
        else                     ln_row_wave(ctx, g2, b2, cn, row - BATCH * SEQ_N);
    }
}

// ---------------- m97-style GEMM body; NT = col-tile width (128 or 64) ------
// MODE 0: C[row*ldC + col] (+bias). MODE 1 (NT=128): transposed output (V^T):
// operand-swapped MFMA -> D^T in regs -> per-wave LDS transpose -> vector stores.
template <int NT, int MODE, typename OutT>
__device__ __forceinline__ void gemm_body(const bf16_t* __restrict__ A,
                                          const bf16_t* __restrict__ Bt,
                                          OutT* __restrict__ C,
                                          const float* __restrict__ bias,
                                          int ldC, int K, int row0, int col0) {
    __shared__ bf16_t As[128 * 64];
    __shared__ bf16_t Bs[NT * 64];
    const int tid = threadIdx.x;
    const int wave = tid >> 6, lane = tid & 63;
    constexpr int WC = NT / 2;      // wave col extent
    constexpr int NJ = WC / 16;     // 4 or 2
    const int wr = (wave >> 1) * 64, wc = (wave & 1) * WC;
    const int quad = lane >> 4, l16 = lane & 15;

    floatx4 acc[4][NJ] = {};

    for (int k0 = 0; k0 < K; k0 += 64) {
#pragma unroll
        for (int p = 0; p < 4; p++) {
            int cA = p * 256 + wave * 64 + lane;
            int rA = cA >> 3, kc = (cA & 7) * 8;
            __builtin_amdgcn_global_load_lds(
                (gptr_t)(A + (size_t)(row0 + rA) * K + k0 + kc),
                (lptr_t)(As + (size_t)(p * 256 + wave * 64) * 8), 16, 0, 0);
            if (p < NT / 32)
                __builtin_amdgcn_global_load_lds(
                    (gptr_t)(Bt + (size_t)(col0 + rA) * K + k0 + kc),
                    (lptr_t)(Bs + (size_t)(p * 256 + wave * 64) * 8), 16, 0, 0);
        }
        __syncthreads();
#pragma unroll
        for (int kt = 0; kt < 2; kt++) {
            bf16x8 aF[4], bF[NJ];
#pragma unroll
            for (int i = 0; i < 4; i++)
                aF[i] = *(bf16x8*)&As[(wr + i * 16 + l16) * 64 + kt * 32 + quad * 8];
#pragma unroll
            for (int j = 0; j < NJ; j++)
                bF[j] = *(bf16x8*)&Bs[(wc + j * 16 + l16) * 64 + kt * 32 + quad * 8];
#pragma unroll
            for (int i = 0; i < 4; i++)
#pragma unroll
                for (int j = 0; j < NJ; j++) {
                    if (MODE == 0)
                        acc[i][j] = __builtin_amdgcn_mfma_f32_16x16x32_bf16(
                            aF[i], bF[j], acc[i][j], 0, 0, 0);
                    else  // transposed output: D^T
                        acc[i][j] = __builtin_amdgcn_mfma_f32_16x16x32_bf16(
                            bF[j], aF[i], acc[i][j], 0, 0, 0);
                }
        }
        __syncthreads();
    }

    if (MODE == 0) {
#pragma unroll
        for (int i = 0; i < 4; i++)
#pragma unroll
            for (int j = 0; j < NJ; j++) {
                int col = col0 + wc + j * 16 + l16;
                float bv = bias ? bias[col] : 0.f;
#pragma unroll
                for (int r = 0; r < 4; r++) {
                    int row = row0 + wr + i * 16 + quad * 4 + r;
                    C[(size_t)row * ldC + col] = (OutT)(acc[i][j][r] + bv);
                }
            }
    } else {
        // lane holds D^T[d_local = j*16+quad*4+r][m_local = i*16+l16] for wave
        // tile (64 m x 64 d). Transpose via per-wave LDS chunk, then vector-store.
        bf16_t* Tw = (wave < 2 ? As : Bs) + (wave & 1) * 4096;  // 64x64, stride 64
#pragma unroll
        for (int i = 0; i < 4; i++)
#pragma unroll
            for (int j = 0; j < 4; j++)
#pragma unroll
                for (int r = 0; r < 4; r++)
                    Tw[(j * 16 + quad * 4 + r) * 64 + i * 16 + l16] = (bf16_t)acc[i][j][r];
        __syncthreads();
        const int grow = row0 + wr;                  // wave m base (64 aligned)
        const int bat = grow >> 11, gm = (grow & 2047) + l16 * 4;
#pragma unroll
        for (int dd = 0; dd < 16; dd++) {
            int d = dd * 4 + quad;
            bf16x4 v = *(bf16x4*)&Tw[d * 64 + l16 * 4];
            int gd = col0 + wc + d - 512;
            *(bf16x4*)(C + ((size_t)bat * 512 + gd) * 2048 + gm) = v;
        }
    }
}

// Fused q/k/v projections: bx 0..3 q -> qb; 4..7 K -> kvb (ld 512); 8..11 V -> Vtg^T
__global__ __launch_bounds__(256) void gemm_qkv_kernel(const bf16_t* __restrict__ xn,
                                                       const bf16_t* __restrict__ cn,
                                                       const bf16_t* __restrict__ Wqt,
                                                       const bf16_t* __restrict__ Wkvt,
                                                       bf16_t* __restrict__ qb,
                                                       bf16_t* __restrict__ kvb,
                                                       bf16_t* __restrict__ Vtg) {
    const int bx = blockIdx.x;
    const int row0 = blockIdx.y * 128;
    if (bx < 4)
        gemm_body<128, 0, bf16_t>(xn, Wqt, qb, nullptr, 512, DIM, row0, bx * 128);
    else if (bx < 8)
        gemm_body<128, 0, bf16_t>(cn, Wkvt, kvb, nullptr, 512, DIM, row0, (bx - 4) * 128);
    else
        gemm_body<128, 1, bf16_t>(cn, Wkvt, Vtg, nullptr, 0, DIM, row0, (bx - 4) * 128);
}

__global__ __launch_bounds__(256) void gemm_out_kernel(const bf16_t* __restrict__ ao,
                                                       const bf16_t* __restrict__ Woutt,
                                                       float* __restrict__ out,
                                                       const float* __restrict__ bias) {
    gemm_body<64, 0, float>(ao, Woutt, out, bias, DIM, INNER,
                            blockIdx.y * 128, blockIdx.x * 64);
}

// ---------------- Flash attention: fixed-base exp2, S^T packed P, reg prefetch
// q: [b,n,512]; kvb: [b,m,512] K-only; Vtg: [(b*8+h)*64+d][m]. o: [b,n,512].
#define PSTR 72
__global__ __launch_bounds__(256) void attn_kernel(const bf16_t* __restrict__ q,
                                                   const bf16_t* __restrict__ kv,
                                                   const bf16_t* __restrict__ Vtg,
                                                   bf16_t* __restrict__ o) {
    __shared__ bf16_t Qs[64 * 72];    // Q staging; reused as per-wave P buffers
    __shared__ bf16_t Ks[64 * 72];    // [krow][d]
    __shared__ bf16_t Vs[64 * 72];    // [d][krow]

    const int b = blockIdx.z, h = blockIdx.y;
    const int n0 = blockIdx.x * 64;
    const int tid = threadIdx.x;
    const int wave = tid >> 6, lane = tid & 63;
    const int quad = lane >> 4, l16 = lane & 15;

    const int sr = (tid >> 3);          // staging row base (0..31)
    const int sc = (tid & 7) * 8;       // staging col

    // stage Q tile [64][64]
#pragma unroll
    for (int p = 0; p < 2; p++) {
        int r = sr + p * 32;
        *(bf16x8*)&Qs[r * 72 + sc] =
            *(const bf16x8*)(q + (size_t)(b * SEQ_N + n0 + r) * INNER + h * DHEAD + sc);
    }

    // ones B-frag for the l-column MFMA: B[k][n=l16] = (l16==0) ? 1 : 0
    bf16x8 bOnes;
    {
        bf16_t ov = (l16 == 0) ? (bf16_t)1.0f : (bf16_t)0.0f;
#pragma unroll
        for (int i = 0; i < 8; i++) bOnes[i] = ov;
    }

    // prefetch K/V tile 0 into registers (pointer-bumped, unconditional)
    const bf16_t* kp = kv + (size_t)(b * SEQ_M) * 512 + h * DHEAD + sc;
    const bf16_t* vp = Vtg + (size_t)((b * HEADS + h) * DHEAD) * SEQ_M + sc;
    bf16x8 kreg[2], vreg[2];
#pragma unroll
    for (int p = 0; p < 2; p++) {
        kreg[p] = *(const bf16x8*)(kp + (size_t)(sr + p * 32) * 512);
        vreg[p] = *(const bf16x8*)(vp + (size_t)(sr + p * 32) * SEQ_M);
    }
    __syncthreads();

    bf16x8 aQ[2];
#pragma unroll
    for (int kt = 0; kt < 2; kt++)
        aQ[kt] = *(bf16x8*)&Qs[(wave * 16 + l16) * 72 + kt * 32 + quad * 8];

    bf16_t* Pw = Qs + wave * (16 * PSTR);   // per-wave P buffer aliasing Qs

    floatx4 oacc[5] = {};   // [0..3]=O d-tiles (unnormalized), [4]=l (col 0)

    for (int it = 0; it < SEQ_M / 64; ++it) {
        __syncthreads();
#pragma unroll
        for (int p = 0; p < 2; p++) {
            int r = sr + p * 32;
            *(bf16x8*)&Ks[r * 72 + sc] = kreg[p];
            *(bf16x8*)&Vs[r * 72 + sc] = vreg[p];
        }
        __syncthreads();

        // unconditional prefetch of next tile (last iter reads into owned ws, unused)
        kp += 64 * 512;
        vp += 64;
#pragma unroll
        for (int p = 0; p < 2; p++) {
            kreg[p] = *(const bf16x8*)(kp + (size_t)(sr + p * 32) * 512);
            vreg[p] = *(const bf16x8*)(vp + (size_t)(sr + p * 32) * SEQ_M);
        }

        // S^T = K @ Q^T (exp2 domain): lane holds S^T[j=jt*16+quad*4+r][q=l16]
        floatx4 s[4] = {};
#pragma unroll
        for (int kt = 0; kt < 2; kt++)
#pragma unroll
            for (int jt = 0; jt < 4; jt++) {
                bf16x8 aK = *(bf16x8*)&Ks[(jt * 16 + l16) * 72 + kt * 32 + quad * 8];
                s[jt] = __builtin_amdgcn_mfma_f32_16x16x32_bf16(aK, aQ[kt], s[jt], 0, 0, 0);
            }

        // P = exp2(S^T): packed b64 stores at P[q=l16][m=jt*16+quad*4]
#pragma unroll
        for (int jt = 0; jt < 4; jt++) {
            bf16x4 pk;
#pragma unroll
            for (int r = 0; r < 4; r++) pk[r] = (bf16_t)exp2f(s[jt][r]);
            *(bf16x4*)&Pw[l16 * PSTR + jt * 16 + quad * 4] = pk;
        }

        // O += P @ V; l via register ones-frag
#pragma unroll
        for (int kt = 0; kt < 2; kt++) {
            bf16x8 aP = *(bf16x8*)&Pw[l16 * PSTR + kt * 32 + quad * 8];
#pragma unroll
            for (int dt = 0; dt < 4; dt++) {
                bf16x8 bV = *(bf16x8*)&Vs[(dt * 16 + l16) * 72 + kt * 32 + quad * 8];
                oacc[dt] = __builtin_amdgcn_mfma_f32_16x16x32_bf16(aP, bV, oacc[dt], 0, 0, 0);
            }
            oacc[4] = __builtin_amdgcn_mfma_f32_16x16x32_bf16(aP, bOnes, oacc[4], 0, 0, 0);
        }
    }

    // epilogue: l in oacc[4] col 0; broadcast within quad-row group
    float inv[4];
#pragma unroll
    for (int r = 0; r < 4; r++) {
        float l = __shfl(oacc[4][r], (int)(lane & 48));
        inv[r] = 1.0f / l;
    }
#pragma unroll
    for (int dt = 0; dt < 4; dt++)
#pragma unroll
        for (int r = 0; r < 4; r++) {
            int row = n0 + wave * 16 + quad * 4 + r;
            int col = h * DHEAD + dt * 16 + l16;
            o[(size_t)(b * SEQ_N + row) * INNER + col] =
                (bf16_t)(oacc[dt][r] * inv[r]);
        }
}

extern "C" void kernel_launch(void* const* d_in, const int* in_sizes, int n_in,
                              void* d_out, int out_size, void* d_ws, size_t ws_size,
                              hipStream_t stream) {
    const float* x    = (const float*)d_in[0];
    const float* ctx  = (const float*)d_in[1];
    const float* g1   = (const float*)d_in[2];
    const float* b1   = (const float*)d_in[3];
    const float* g2   = (const float*)d_in[4];
    const float* b2   = (const float*)d_in[5];
    const float* Wq   = (const float*)d_in[6];
    const float* Wkv  = (const float*)d_in[7];
    const float* Wout = (const float*)d_in[8];
    const float* bout = (const float*)d_in[9];
    float* out = (float*)d_out;

    const int rows = BATCH * SEQ_N;  // 8192
    bf16_t* xn    = (bf16_t*)d_ws;                       // 8M elem; reused as attn out
    bf16_t* cn    = xn + (size_t)rows * DIM;             // 8M
    bf16_t* qb    = cn + (size_t)rows * DIM;             // 4M
    bf16_t* kvb   = qb + (size_t)rows * INNER;           // 4M (K only, stride 512)
    bf16_t* Vtg   = kvb + (size_t)rows * INNER;          // 4M (V transposed)
    bf16_t* Wqt   = Vtg + (size_t)rows * INNER;          // 0.5M
    bf16_t* Wkvt  = Wqt + (size_t)INNER * DIM;           // 1M
    bf16_t* Woutt = Wkvt + (size_t)(2 * INNER) * DIM;    // 0.5M
    bf16_t* o_attn = xn;  // alias: xn dead after qkv GEMM

    prep_kernel<<<512 + (2 * rows) / 4, 256, 0, stream>>>(
        x, ctx, g1, b1, g2, b2, Wq, Wkv, Wout, xn, cn, Wqt, Wkvt, Woutt);
    gemm_qkv_kernel<<<dim3(12, rows / 128), 256, 0, stream>>>(
        xn, cn, Wqt, Wkvt, qb, kvb, Vtg);
    attn_kernel<<<dim3(SEQ_N / 64, HEADS, BATCH), 256, 0, stream>>>(qb, kvb, Vtg, o_attn);
    gemm_out_kernel<<<dim3(DIM / 64, rows / 128), 256, 0, stream>>>(o_attn, Woutt, out, bout);
}